// Round 1
// baseline (4057.492 us; speedup 1.0000x reference)
//
#include <hip/hip_runtime.h>

using u16 = unsigned short;
using u32 = unsigned int;
typedef __attribute__((ext_vector_type(8))) short bf16x8;
typedef __attribute__((ext_vector_type(4))) float f32x4;

#define B_ 32
#define T_ 128
#define E_ 512
#define H_ 1024
#define V_ 32000
#define NROW 4096                 // B*T rows, r = b*128 + t  (b-major)
#define BTV ((size_t)B_ * T_ * V_)
#define NBLK_REC 128

__device__ __forceinline__ u16 f2bf(float f) {
  u32 x = __float_as_uint(f);
  x += 0x7FFFu + ((x >> 16) & 1u);
  return (u16)(x >> 16);
}

__device__ __forceinline__ void gload_lds16(const void* g, void* l) {
  __builtin_amdgcn_global_load_lds(
      (const __attribute__((address_space(1))) u32*)g,
      (__attribute__((address_space(3))) u32*)l, 16, 0, 0);
}

// ---------------- prep: f32 -> bf16 cast (vectorized) ----------------
__global__ void cast_bf16_kernel(const float* __restrict__ src, u16* __restrict__ dst, int n4) {
  int i = blockIdx.x * blockDim.x + threadIdx.x;
  int stride = gridDim.x * blockDim.x;
  for (; i < n4; i += stride) {
    float4 v = reinterpret_cast<const float4*>(src)[i];
    u32 p0 = (u32)f2bf(v.x) | ((u32)f2bf(v.y) << 16);
    u32 p1 = (u32)f2bf(v.z) | ((u32)f2bf(v.w) << 16);
    reinterpret_cast<uint2*>(dst)[i] = make_uint2(p0, p1);
  }
}

// ---------------- prep: X = bf16(relu(emb[tok])), rows r=b*128+t ----------------
__global__ void embed_kernel(const int* __restrict__ tgt, const float* __restrict__ emb,
                             u16* __restrict__ X) {
  int r = blockIdx.x * 2 + (threadIdx.x >> 7);  // 0..4095
  int c = threadIdx.x & 127;                    // float4 index in row (E=512 -> 128)
  int t = r & 127;
  int tok = (t == 0) ? 1 : tgt[r - 1];          // BOS=1 ; tgt[b*128 + (t-1)]
  float4 v = reinterpret_cast<const float4*>(emb + (size_t)tok * E_)[c];
  u32 p0 = (u32)f2bf(fmaxf(v.x, 0.f)) | ((u32)f2bf(fmaxf(v.y, 0.f)) << 16);
  u32 p1 = (u32)f2bf(fmaxf(v.z, 0.f)) | ((u32)f2bf(fmaxf(v.w, 0.f)) << 16);
  reinterpret_cast<uint2*>(X + (size_t)r * E_)[c] = make_uint2(p0, p1);
}

// ---------------- bf16 MFMA GEMM, C[M=4096][N] = A[M][K] @ B[N][K]^T + bias ----------------
// 128x128 tile, BK=32, 4 waves (64x64 quadrants), global_load_lds staging (m97 structure)
__global__ __launch_bounds__(256)
void gemm_bt_kernel(const u16* __restrict__ A, const u16* __restrict__ B,
                    const float* __restrict__ bias, float* __restrict__ C,
                    int K, int N) {
  __shared__ __align__(16) u16 As[128 * 32];
  __shared__ __align__(16) u16 Bs[128 * 32];
  int bid = blockIdx.x;
  int mtile = bid & 31, ntile = bid >> 5;       // grid = ntiles*32 ; 32 consecutive bids share B-tile
  int m0 = mtile << 7, n0 = ntile << 7;
  int tid = threadIdx.x, wv = tid >> 6, ln = tid & 63;
  int lr = ln & 15, lg = ln >> 4;
  int wrow = (wv >> 1) << 6, wcol = (wv & 1) << 6;

  f32x4 acc[4][4];
#pragma unroll
  for (int m = 0; m < 4; ++m)
#pragma unroll
    for (int n = 0; n < 4; ++n) acc[m][n] = (f32x4){0.f, 0.f, 0.f, 0.f};

  // staging: 512 chunks of 16B per tile; chunk c -> row c>>2, seg c&3 ; thread stages c=tid, tid+256
  int c0 = tid, c1 = tid + 256;
  const u16* gA0 = A + (size_t)(m0 + (c0 >> 2)) * K + ((c0 & 3) << 3);
  const u16* gA1 = A + (size_t)(m0 + (c1 >> 2)) * K + ((c1 & 3) << 3);
  const u16* gB0 = B + (size_t)(n0 + (c0 >> 2)) * K + ((c0 & 3) << 3);
  const u16* gB1 = B + (size_t)(n0 + (c1 >> 2)) * K + ((c1 & 3) << 3);
  u16* lA0 = As + (wv << 9);          // wave-uniform LDS bases (HW adds lane*16B)
  u16* lA1 = As + 2048 + (wv << 9);
  u16* lB0 = Bs + (wv << 9);
  u16* lB1 = Bs + 2048 + (wv << 9);

  for (int k0 = 0; k0 < K; k0 += 32) {
    gload_lds16(gA0 + k0, lA0);
    gload_lds16(gA1 + k0, lA1);
    gload_lds16(gB0 + k0, lB0);
    gload_lds16(gB1 + k0, lB1);
    __syncthreads();
    bf16x8 a[4], b[4];
#pragma unroll
    for (int m = 0; m < 4; ++m)
      a[m] = *reinterpret_cast<const bf16x8*>(&As[(wrow + (m << 4) + lr) * 32 + (lg << 3)]);
#pragma unroll
    for (int n = 0; n < 4; ++n)
      b[n] = *reinterpret_cast<const bf16x8*>(&Bs[(wcol + (n << 4) + lr) * 32 + (lg << 3)]);
#pragma unroll
    for (int m = 0; m < 4; ++m)
#pragma unroll
      for (int n = 0; n < 4; ++n)
        acc[m][n] = __builtin_amdgcn_mfma_f32_16x16x32_bf16(a[m], b[n], acc[m][n], 0, 0, 0);
    __syncthreads();
  }

  // epilogue: C row = global row (rows are b-major so logits write is linear)
#pragma unroll
  for (int m = 0; m < 4; ++m) {
    int rowb = m0 + wrow + (m << 4) + (lg << 2);
#pragma unroll
    for (int n = 0; n < 4; ++n) {
      int col = n0 + wcol + (n << 4) + lr;
      float bv = bias[col];
#pragma unroll
      for (int i = 0; i < 4; ++i)
        C[(size_t)(rowb + i) * N + col] = acc[m][n][i] + bv;
    }
  }
}

// ---------------- persistent GRU recurrence ----------------
__device__ __forceinline__ void grid_bar(u32* bar, u32 target) {
  __threadfence();
  __syncthreads();
  if (threadIdx.x == 0) {
    __hip_atomic_fetch_add(bar, 1u, __ATOMIC_RELEASE, __HIP_MEMORY_SCOPE_AGENT);
    while (__hip_atomic_load(bar, __ATOMIC_ACQUIRE, __HIP_MEMORY_SCOPE_AGENT) < target)
      __builtin_amdgcn_s_sleep(2);
  }
  __syncthreads();
  __threadfence();
}

__device__ __forceinline__ float sigm(float x) { return 1.f / (1.f + __expf(-x)); }

__global__ __launch_bounds__(256, 1)
void recur_kernel(const u16* __restrict__ Whh16, const float* __restrict__ Gi,
                  const float* __restrict__ bhh, const float* __restrict__ enc_h,
                  u16* __restrict__ hb16, u16* __restrict__ Hall,
                  float* __restrict__ outTail, u32* __restrict__ bar) {
  int bid = blockIdx.x;               // 128 blocks
  int xcd = bid & 7, idx = bid >> 3;
  int tj = xcd * 8 + (idx & 7);       // j-tile 0..63 (XCD-local W slice)
  int tb = idx >> 3;                  // b-tile 0..1
  int tid = threadIdx.x, wv = tid >> 6, ln = tid & 63;
  int lr = ln & 15, lg = ln >> 4;
  int b0 = tb << 4, j0 = tj << 4;
  int kb = wv << 8;                   // K-slice per wave: 256

  __shared__ float red[3 * 4 * 256];  // [gate][wave][row16][col16]

  // preload W_hh fragments for all 128 steps (3 gates x 8 kk) into registers
  bf16x8 wf[3][8];
  const u16* wb = Whh16 + (size_t)(j0 + lr) * H_ + kb + (lg << 3);
#pragma unroll
  for (int g = 0; g < 3; ++g)
#pragma unroll
    for (int kk = 0; kk < 8; ++kk)
      wf[g][kk] = *reinterpret_cast<const bf16x8*>(wb + (size_t)g * H_ * H_ + kk * 32);

  // this thread owns h element (bb, jj)
  int row = tid >> 4, colj = tid & 15;
  int bb = b0 + row, jj = j0 + colj;
  float hreg = enc_h[bb * H_ + jj];
  float bhr = bhh[jj], bhz = bhh[H_ + jj], bhn = bhh[2 * H_ + jj];

  for (int t = 0; t < T_; ++t) {
    int cur = t & 1, nxt = cur ^ 1;
    // prefetch gi (independent of h)
    size_t gib = (size_t)(bb * T_ + t) * (3 * H_) + jj;
    float gir = Gi[gib], giz = Gi[gib + H_], gin = Gi[gib + 2 * H_];

    const u16* hb = hb16 + cur * (B_ * H_) + (b0 + lr) * H_ + kb + (lg << 3);
    f32x4 aR = (f32x4){0.f, 0.f, 0.f, 0.f};
    f32x4 aZ = aR, aN = aR;
#pragma unroll
    for (int kk = 0; kk < 8; ++kk) {
      bf16x8 af = *reinterpret_cast<const bf16x8*>(hb + kk * 32);
      aR = __builtin_amdgcn_mfma_f32_16x16x32_bf16(af, wf[0][kk], aR, 0, 0, 0);
      aZ = __builtin_amdgcn_mfma_f32_16x16x32_bf16(af, wf[1][kk], aZ, 0, 0, 0);
      aN = __builtin_amdgcn_mfma_f32_16x16x32_bf16(af, wf[2][kk], aN, 0, 0, 0);
    }
#pragma unroll
    for (int i = 0; i < 4; ++i) {
      int rr = ((lg << 2) + i) * 16 + lr;
      red[(0 * 4 + wv) * 256 + rr] = aR[i];
      red[(1 * 4 + wv) * 256 + rr] = aZ[i];
      red[(2 * 4 + wv) * 256 + rr] = aN[i];
    }
    __syncthreads();
    float sr = red[0 * 1024 + 0 * 256 + tid] + red[0 * 1024 + 1 * 256 + tid] +
               red[0 * 1024 + 2 * 256 + tid] + red[0 * 1024 + 3 * 256 + tid];
    float sz = red[1 * 1024 + 0 * 256 + tid] + red[1 * 1024 + 1 * 256 + tid] +
               red[1 * 1024 + 2 * 256 + tid] + red[1 * 1024 + 3 * 256 + tid];
    float sn = red[2 * 1024 + 0 * 256 + tid] + red[2 * 1024 + 1 * 256 + tid] +
               red[2 * 1024 + 2 * 256 + tid] + red[2 * 1024 + 3 * 256 + tid];

    float r = sigm(gir + sr + bhr);
    float z = sigm(giz + sz + bhz);
    float narg = gin + r * (sn + bhn);
    float n = 2.f / (1.f + __expf(-2.f * narg)) - 1.f;  // tanh
    hreg = (1.f - z) * n + z * hreg;

    hb16[nxt * (B_ * H_) + bb * H_ + jj] = f2bf(hreg);
    Hall[(size_t)(bb * T_ + t) * H_ + jj] = f2bf(hreg);
    if (t == T_ - 1) outTail[bb * H_ + jj] = hreg;
    if (t != T_ - 1) grid_bar(bar, (u32)(t + 1) * NBLK_REC);
  }
}

// ---------------- log-softmax: pass1 online LSE per row ----------------
__global__ __launch_bounds__(256)
void lse_pass1_kernel(const float* __restrict__ out, float* __restrict__ lse) {
  int r = blockIdx.x;  // 4096 rows
  const float4* src = reinterpret_cast<const float4*>(out + (size_t)r * V_);
  float M = -1e30f, S = 0.f;
  for (int i = threadIdx.x; i < V_ / 4; i += 256) {
    float4 v = src[i];
    float m4 = fmaxf(fmaxf(v.x, v.y), fmaxf(v.z, v.w));
    if (m4 > M) { S *= __expf(M - m4); M = m4; }
    S += __expf(v.x - M) + __expf(v.y - M) + __expf(v.z - M) + __expf(v.w - M);
  }
#pragma unroll
  for (int o = 32; o; o >>= 1) {
    float Mo = __shfl_xor(M, o);
    float So = __shfl_xor(S, o);
    float Mn = fmaxf(M, Mo);
    S = S * __expf(M - Mn) + So * __expf(Mo - Mn);
    M = Mn;
  }
  __shared__ float tM[4], tS[4];
  if ((threadIdx.x & 63) == 0) { tM[threadIdx.x >> 6] = M; tS[threadIdx.x >> 6] = S; }
  __syncthreads();
  if (threadIdx.x == 0) {
    float Mf = tM[0], Sf = tS[0];
    for (int w = 1; w < 4; ++w) {
      float Mn = fmaxf(Mf, tM[w]);
      Sf = Sf * __expf(Mf - Mn) + tS[w] * __expf(tM[w] - Mn);
      Mf = Mn;
    }
    lse[r] = Mf + __logf(Sf);
  }
}

// ---------------- log-softmax: pass2 subtract ----------------
__global__ __launch_bounds__(1024)
void lse_pass2_kernel(float* __restrict__ out, const float* __restrict__ lse) {
  int r = blockIdx.x;
  float l = lse[r];
  float4* p = reinterpret_cast<float4*>(out + (size_t)r * V_);
  for (int i = threadIdx.x; i < V_ / 4; i += 1024) {
    float4 v = p[i];
    v.x -= l; v.y -= l; v.z -= l; v.w -= l;
    p[i] = v;
  }
}

// ---------------- host ----------------
extern "C" void kernel_launch(void* const* d_in, const int* in_sizes, int n_in,
                              void* d_out, int out_size, void* d_ws, size_t ws_size,
                              hipStream_t stream) {
  const float* enc_h = (const float*)d_in[1];
  const int*   tgt   = (const int*)d_in[2];
  const float* emb   = (const float*)d_in[3];
  const float* Wih   = (const float*)d_in[4];
  const float* Whh   = (const float*)d_in[5];
  const float* bih   = (const float*)d_in[6];
  const float* bhh   = (const float*)d_in[7];
  const float* Wout  = (const float*)d_in[8];
  const float* bout  = (const float*)d_in[9];
  float* out = (float*)d_out;

  char* ws = (char*)d_ws;
  size_t off = 0;
  auto alloc = [&](size_t bytes) -> void* {
    void* p = ws + off;
    off = (off + bytes + 255) & ~(size_t)255;
    return p;
  };
  u32*  bar    = (u32*)alloc(256);
  u16*  Wih16  = (u16*)alloc((size_t)3 * H_ * E_ * 2);
  u16*  Whh16  = (u16*)alloc((size_t)3 * H_ * H_ * 2);
  u16*  Wout16 = (u16*)alloc((size_t)V_ * H_ * 2);
  u16*  X16    = (u16*)alloc((size_t)NROW * E_ * 2);
  u16*  Hall   = (u16*)alloc((size_t)NROW * H_ * 2);
  u16*  hb16   = (u16*)alloc((size_t)2 * B_ * H_ * 2);
  float* Gi    = (float*)alloc((size_t)NROW * 3 * H_ * 4);
  float* lseA  = (float*)alloc((size_t)NROW * 4);

  hipMemsetAsync(bar, 0, 256, stream);
  cast_bf16_kernel<<<1024, 256, 0, stream>>>(Wih, Wih16, 3 * H_ * E_ / 4);
  cast_bf16_kernel<<<1024, 256, 0, stream>>>(Whh, Whh16, 3 * H_ * H_ / 4);
  cast_bf16_kernel<<<2048, 256, 0, stream>>>(Wout, Wout16, V_ * H_ / 4);
  cast_bf16_kernel<<<32, 256, 0, stream>>>(enc_h, hb16, B_ * H_ / 4);  // h buffer 0
  embed_kernel<<<NROW / 2, 256, 0, stream>>>(tgt, emb, X16);

  // Gi = X @ W_ih^T + b_ih   (M=4096, N=3072, K=512)
  gemm_bt_kernel<<<(3 * H_ / 128) * 32, 256, 0, stream>>>(X16, Wih16, bih, Gi, E_, 3 * H_);

  recur_kernel<<<NBLK_REC, 256, 0, stream>>>(Whh16, Gi, bhh, enc_h, hb16, Hall,
                                             out + BTV, bar);

  // logits = Hall @ W_out^T + b_out -> d_out  (M=4096, N=32000, K=1024)
  gemm_bt_kernel<<<(V_ / 128) * 32, 256, 0, stream>>>(Hall, Wout16, bout, out, H_, V_);

  lse_pass1_kernel<<<NROW, 256, 0, stream>>>(out, lseA);
  lse_pass2_kernel<<<NROW, 1024, 0, stream>>>(out, lseA);
}

// Round 2
// 1588.109 us; speedup vs baseline: 2.5549x; 2.5549x over previous
//
#include <hip/hip_runtime.h>

using u16 = unsigned short;
using u32 = unsigned int;
typedef __attribute__((ext_vector_type(8))) short bf16x8;
typedef __attribute__((ext_vector_type(4))) float f32x4;

#define B_ 32
#define T_ 128
#define E_ 512
#define H_ 1024
#define V_ 32000
#define NROW 4096                 // B*T rows, r = b*128 + t  (b-major)
#define BTV ((size_t)B_ * T_ * V_)
#define NBLK_REC 32               // recurrence blocks; each owns 32 h-columns

__device__ __forceinline__ u16 f2bf(float f) {
  u32 x = __float_as_uint(f);
  x += 0x7FFFu + ((x >> 16) & 1u);
  return (u16)(x >> 16);
}

__device__ __forceinline__ void gload_lds16(const void* g, void* l) {
  __builtin_amdgcn_global_load_lds(
      (const __attribute__((address_space(1))) u32*)g,
      (__attribute__((address_space(3))) u32*)l, 16, 0, 0);
}

// ---------------- prep: f32 -> bf16 cast (vectorized) ----------------
__global__ void cast_bf16_kernel(const float* __restrict__ src, u16* __restrict__ dst, int n4) {
  int i = blockIdx.x * blockDim.x + threadIdx.x;
  int stride = gridDim.x * blockDim.x;
  for (; i < n4; i += stride) {
    float4 v = reinterpret_cast<const float4*>(src)[i];
    u32 p0 = (u32)f2bf(v.x) | ((u32)f2bf(v.y) << 16);
    u32 p1 = (u32)f2bf(v.z) | ((u32)f2bf(v.w) << 16);
    reinterpret_cast<uint2*>(dst)[i] = make_uint2(p0, p1);
  }
}

// ---------------- prep: X = bf16(relu(emb[tok])), rows r=b*128+t ----------------
__global__ void embed_kernel(const int* __restrict__ tgt, const float* __restrict__ emb,
                             u16* __restrict__ X) {
  int r = blockIdx.x * 2 + (threadIdx.x >> 7);  // 0..4095
  int c = threadIdx.x & 127;                    // float4 index in row (E=512 -> 128)
  int t = r & 127;
  int tok = (t == 0) ? 1 : tgt[r - 1];          // BOS=1 ; tgt[b*128 + (t-1)]
  float4 v = reinterpret_cast<const float4*>(emb + (size_t)tok * E_)[c];
  u32 p0 = (u32)f2bf(fmaxf(v.x, 0.f)) | ((u32)f2bf(fmaxf(v.y, 0.f)) << 16);
  u32 p1 = (u32)f2bf(fmaxf(v.z, 0.f)) | ((u32)f2bf(fmaxf(v.w, 0.f)) << 16);
  reinterpret_cast<uint2*>(X + (size_t)r * E_)[c] = make_uint2(p0, p1);
}

// ---------------- bf16 MFMA GEMM, C[M=4096][N] = A[M][K] @ B[N][K]^T + bias ----------------
// 128x128 tile, BK=32, 4 waves (64x64 quadrants), global_load_lds staging (m97 structure)
__global__ __launch_bounds__(256)
void gemm_bt_kernel(const u16* __restrict__ A, const u16* __restrict__ B,
                    const float* __restrict__ bias, float* __restrict__ C,
                    int K, int N) {
  __shared__ __align__(16) u16 As[128 * 32];
  __shared__ __align__(16) u16 Bs[128 * 32];
  int bid = blockIdx.x;
  int mtile = bid & 31, ntile = bid >> 5;       // grid = ntiles*32 ; 32 consecutive bids share B-tile
  int m0 = mtile << 7, n0 = ntile << 7;
  int tid = threadIdx.x, wv = tid >> 6, ln = tid & 63;
  int lr = ln & 15, lg = ln >> 4;
  int wrow = (wv >> 1) << 6, wcol = (wv & 1) << 6;

  f32x4 acc[4][4];
#pragma unroll
  for (int m = 0; m < 4; ++m)
#pragma unroll
    for (int n = 0; n < 4; ++n) acc[m][n] = (f32x4){0.f, 0.f, 0.f, 0.f};

  int c0 = tid, c1 = tid + 256;
  const u16* gA0 = A + (size_t)(m0 + (c0 >> 2)) * K + ((c0 & 3) << 3);
  const u16* gA1 = A + (size_t)(m0 + (c1 >> 2)) * K + ((c1 & 3) << 3);
  const u16* gB0 = B + (size_t)(n0 + (c0 >> 2)) * K + ((c0 & 3) << 3);
  const u16* gB1 = B + (size_t)(n0 + (c1 >> 2)) * K + ((c1 & 3) << 3);
  u16* lA0 = As + (wv << 9);          // wave-uniform LDS bases (HW adds lane*16B)
  u16* lA1 = As + 2048 + (wv << 9);
  u16* lB0 = Bs + (wv << 9);
  u16* lB1 = Bs + 2048 + (wv << 9);

  for (int k0 = 0; k0 < K; k0 += 32) {
    gload_lds16(gA0 + k0, lA0);
    gload_lds16(gA1 + k0, lA1);
    gload_lds16(gB0 + k0, lB0);
    gload_lds16(gB1 + k0, lB1);
    __syncthreads();
    bf16x8 a[4], b[4];
#pragma unroll
    for (int m = 0; m < 4; ++m)
      a[m] = *reinterpret_cast<const bf16x8*>(&As[(wrow + (m << 4) + lr) * 32 + (lg << 3)]);
#pragma unroll
    for (int n = 0; n < 4; ++n)
      b[n] = *reinterpret_cast<const bf16x8*>(&Bs[(wcol + (n << 4) + lr) * 32 + (lg << 3)]);
#pragma unroll
    for (int m = 0; m < 4; ++m)
#pragma unroll
      for (int n = 0; n < 4; ++n)
        acc[m][n] = __builtin_amdgcn_mfma_f32_16x16x32_bf16(a[m], b[n], acc[m][n], 0, 0, 0);
    __syncthreads();
  }

#pragma unroll
  for (int m = 0; m < 4; ++m) {
    int rowb = m0 + wrow + (m << 4) + (lg << 2);
#pragma unroll
    for (int n = 0; n < 4; ++n) {
      int col = n0 + wcol + (n << 4) + lr;
      float bv = bias[col];
#pragma unroll
      for (int i = 0; i < 4; ++i)
        C[(size_t)(rowb + i) * N + col] = acc[m][n][i] + bv;
    }
  }
}

// ---------------- persistent GRU recurrence, 32 blocks, flag-based sync ----------------
__device__ __forceinline__ float sigm(float x) { return 1.f / (1.f + __expf(-x)); }

__global__ __launch_bounds__(256, 1)
void recur_kernel(const u16* __restrict__ Whh16, const float* __restrict__ Gi,
                  const float* __restrict__ bhh, const float* __restrict__ enc_h,
                  u16* __restrict__ hb16, u16* __restrict__ Hall,
                  float* __restrict__ outTail, u32* __restrict__ flags) {
  int bid = blockIdx.x;               // 0..31 ; owns h columns [bid*32, bid*32+32)
  int tid = threadIdx.x, wv = tid >> 6, ln = tid & 63;
  int lr = ln & 15, lg = ln >> 4;
  int j0 = bid << 5;
  int kb = wv << 8;                   // K-slice per wave: 256

  __shared__ float red[4][2][6][256]; // [wave][Mtile][Ntile(g*2+nh)][row16*16+col16]

  // preload W_hh fragments: 6 N-tiles (3 gates x 2) x 8 kk = 192 VGPRs/lane
  bf16x8 wf[6][8];
#pragma unroll
  for (int g = 0; g < 3; ++g)
#pragma unroll
    for (int nh = 0; nh < 2; ++nh) {
      const u16* wrow = Whh16 + (size_t)(g * H_ + j0 + nh * 16 + lr) * H_ + kb + (lg << 3);
#pragma unroll
      for (int kk = 0; kk < 8; ++kk)
        wf[g * 2 + nh][kk] = *reinterpret_cast<const bf16x8*>(wrow + kk * 32);
    }

  // gate-math ownership: thread -> (batch bb, 4 cols j0+j4..j0+j4+3)
  int bb = tid >> 3;
  int j4 = (tid & 7) << 2;
  float4 bhr = *reinterpret_cast<const float4*>(bhh + 0 * H_ + j0 + j4);
  float4 bhz = *reinterpret_cast<const float4*>(bhh + 1 * H_ + j0 + j4);
  float4 bhn = *reinterpret_cast<const float4*>(bhh + 2 * H_ + j0 + j4);
  float4 hp = *reinterpret_cast<const float4*>(enc_h + bb * H_ + j0 + j4);

  for (int t = 0; t < T_; ++t) {
    int cur = t & 1, nxt = cur ^ 1;

    // Gi prefetch (independent of h) -- issued before the poll
    const float* gib = Gi + (size_t)(bb * T_ + t) * (3 * H_) + j0 + j4;
    float4 gir = *reinterpret_cast<const float4*>(gib + 0 * H_);
    float4 giz = *reinterpret_cast<const float4*>(gib + 1 * H_);
    float4 gin = *reinterpret_cast<const float4*>(gib + 2 * H_);

    if (t > 0) {
      if (tid < NBLK_REC) {
        while (__hip_atomic_load(&flags[tid * 16], __ATOMIC_ACQUIRE,
                                 __HIP_MEMORY_SCOPE_AGENT) < (u32)t)
          __builtin_amdgcn_s_sleep(1);
      }
      __syncthreads();  // acquire-inv by wave 0 done before any wave's h loads
    }

    // per-wave K-slice GEMV: direct per-lane A loads, no LDS staging
    const u16* hbase = hb16 + (size_t)cur * (B_ * H_) + kb + (lg << 3);
    f32x4 acc[2][6];
#pragma unroll
    for (int mt = 0; mt < 2; ++mt)
#pragma unroll
      for (int tn = 0; tn < 6; ++tn) acc[mt][tn] = (f32x4){0.f, 0.f, 0.f, 0.f};
#pragma unroll
    for (int kk = 0; kk < 8; ++kk) {
      bf16x8 a0 = *reinterpret_cast<const bf16x8*>(hbase + (size_t)lr * H_ + kk * 32);
      bf16x8 a1 = *reinterpret_cast<const bf16x8*>(hbase + (size_t)(16 + lr) * H_ + kk * 32);
#pragma unroll
      for (int tn = 0; tn < 6; ++tn) {
        acc[0][tn] = __builtin_amdgcn_mfma_f32_16x16x32_bf16(a0, wf[tn][kk], acc[0][tn], 0, 0, 0);
        acc[1][tn] = __builtin_amdgcn_mfma_f32_16x16x32_bf16(a1, wf[tn][kk], acc[1][tn], 0, 0, 0);
      }
    }

    // cross-wave K reduction in LDS
#pragma unroll
    for (int mt = 0; mt < 2; ++mt)
#pragma unroll
      for (int tn = 0; tn < 6; ++tn)
#pragma unroll
        for (int i = 0; i < 4; ++i)
          red[wv][mt][tn][((lg << 2) + i) * 16 + lr] = acc[mt][tn][i];
    __syncthreads();

    int mt = bb >> 4;
    int nh = j4 >> 4;
    int rbase = (bb & 15) * 16 + (j4 & 15);
    float4 s[3];
#pragma unroll
    for (int g = 0; g < 3; ++g) {
      float4 a4 = make_float4(0.f, 0.f, 0.f, 0.f);
#pragma unroll
      for (int w = 0; w < 4; ++w) {
        float4 v = *reinterpret_cast<const float4*>(&red[w][mt][g * 2 + nh][rbase]);
        a4.x += v.x; a4.y += v.y; a4.z += v.z; a4.w += v.w;
      }
      s[g] = a4;
    }
    __syncthreads();  // red reads done before next step's writes

    // gate math (4 elements)
    float hn[4];
    {
      float r0 = sigm(gir.x + s[0].x + bhr.x);
      float r1 = sigm(gir.y + s[0].y + bhr.y);
      float r2 = sigm(gir.z + s[0].z + bhr.z);
      float r3 = sigm(gir.w + s[0].w + bhr.w);
      float z0 = sigm(giz.x + s[1].x + bhz.x);
      float z1 = sigm(giz.y + s[1].y + bhz.y);
      float z2 = sigm(giz.z + s[1].z + bhz.z);
      float z3 = sigm(giz.w + s[1].w + bhz.w);
      float a0 = gin.x + r0 * (s[2].x + bhn.x);
      float a1 = gin.y + r1 * (s[2].y + bhn.y);
      float a2 = gin.z + r2 * (s[2].z + bhn.z);
      float a3 = gin.w + r3 * (s[2].w + bhn.w);
      float n0 = 2.f / (1.f + __expf(-2.f * a0)) - 1.f;
      float n1 = 2.f / (1.f + __expf(-2.f * a1)) - 1.f;
      float n2 = 2.f / (1.f + __expf(-2.f * a2)) - 1.f;
      float n3 = 2.f / (1.f + __expf(-2.f * a3)) - 1.f;
      hn[0] = (1.f - z0) * n0 + z0 * hp.x;
      hn[1] = (1.f - z1) * n1 + z1 * hp.y;
      hn[2] = (1.f - z2) * n2 + z2 * hp.z;
      hn[3] = (1.f - z3) * n3 + z3 * hp.w;
      hp = make_float4(hn[0], hn[1], hn[2], hn[3]);
    }

    u32 p0 = (u32)f2bf(hn[0]) | ((u32)f2bf(hn[1]) << 16);
    u32 p1 = (u32)f2bf(hn[2]) | ((u32)f2bf(hn[3]) << 16);

    // Hall (consumed by later kernel; plain store)
    reinterpret_cast<uint2*>(Hall + (size_t)(bb * T_ + t) * H_ + j0 + j4)[0] = make_uint2(p0, p1);

    if (t < T_ - 1) {
      // h exchange: write-through agent-scope word stores (no cache-wide release fence)
      u32* hw = (u32*)(hb16 + (size_t)nxt * (B_ * H_) + bb * H_ + j0 + j4);
      __hip_atomic_store(hw + 0, p0, __ATOMIC_RELAXED, __HIP_MEMORY_SCOPE_AGENT);
      __hip_atomic_store(hw + 1, p1, __ATOMIC_RELAXED, __HIP_MEMORY_SCOPE_AGENT);
      __syncthreads();  // drains vmcnt(0) per thread -> all stores at coherence point
      if (tid == 0)
        __hip_atomic_store(&flags[bid * 16], (u32)(t + 1), __ATOMIC_RELEASE,
                           __HIP_MEMORY_SCOPE_AGENT);
    } else {
      reinterpret_cast<float4*>(outTail + (size_t)bb * H_ + j0 + j4)[0] = hp;
    }
  }
}

// ---------------- log-softmax: pass1 online LSE per row ----------------
__global__ __launch_bounds__(256)
void lse_pass1_kernel(const float* __restrict__ out, float* __restrict__ lse) {
  int r = blockIdx.x;  // 4096 rows
  const float4* src = reinterpret_cast<const float4*>(out + (size_t)r * V_);
  float M = -1e30f, S = 0.f;
  for (int i = threadIdx.x; i < V_ / 4; i += 256) {
    float4 v = src[i];
    float m4 = fmaxf(fmaxf(v.x, v.y), fmaxf(v.z, v.w));
    if (m4 > M) { S *= __expf(M - m4); M = m4; }
    S += __expf(v.x - M) + __expf(v.y - M) + __expf(v.z - M) + __expf(v.w - M);
  }
#pragma unroll
  for (int o = 32; o; o >>= 1) {
    float Mo = __shfl_xor(M, o);
    float So = __shfl_xor(S, o);
    float Mn = fmaxf(M, Mo);
    S = S * __expf(M - Mn) + So * __expf(Mo - Mn);
    M = Mn;
  }
  __shared__ float tM[4], tS[4];
  if ((threadIdx.x & 63) == 0) { tM[threadIdx.x >> 6] = M; tS[threadIdx.x >> 6] = S; }
  __syncthreads();
  if (threadIdx.x == 0) {
    float Mf = tM[0], Sf = tS[0];
    for (int w = 1; w < 4; ++w) {
      float Mn = fmaxf(Mf, tM[w]);
      Sf = Sf * __expf(Mf - Mn) + tS[w] * __expf(tM[w] - Mn);
      Mf = Mn;
    }
    lse[r] = Mf + __logf(Sf);
  }
}

// ---------------- log-softmax: pass2 subtract ----------------
__global__ __launch_bounds__(1024)
void lse_pass2_kernel(float* __restrict__ out, const float* __restrict__ lse) {
  int r = blockIdx.x;
  float l = lse[r];
  float4* p = reinterpret_cast<float4*>(out + (size_t)r * V_);
  for (int i = threadIdx.x; i < V_ / 4; i += 1024) {
    float4 v = p[i];
    v.x -= l; v.y -= l; v.z -= l; v.w -= l;
    p[i] = v;
  }
}

// ---------------- host ----------------
extern "C" void kernel_launch(void* const* d_in, const int* in_sizes, int n_in,
                              void* d_out, int out_size, void* d_ws, size_t ws_size,
                              hipStream_t stream) {
  const float* enc_h = (const float*)d_in[1];
  const int*   tgt   = (const int*)d_in[2];
  const float* emb   = (const float*)d_in[3];
  const float* Wih   = (const float*)d_in[4];
  const float* Whh   = (const float*)d_in[5];
  const float* bih   = (const float*)d_in[6];
  const float* bhh   = (const float*)d_in[7];
  const float* Wout  = (const float*)d_in[8];
  const float* bout  = (const float*)d_in[9];
  float* out = (float*)d_out;

  char* ws = (char*)d_ws;
  size_t off = 0;
  auto alloc = [&](size_t bytes) -> void* {
    void* p = ws + off;
    off = (off + bytes + 255) & ~(size_t)255;
    return p;
  };
  u32*  flags  = (u32*)alloc(4096);
  u16*  Wih16  = (u16*)alloc((size_t)3 * H_ * E_ * 2);
  u16*  Whh16  = (u16*)alloc((size_t)3 * H_ * H_ * 2);
  u16*  Wout16 = (u16*)alloc((size_t)V_ * H_ * 2);
  u16*  X16    = (u16*)alloc((size_t)NROW * E_ * 2);
  u16*  Hall   = (u16*)alloc((size_t)NROW * H_ * 2);
  u16*  hb16   = (u16*)alloc((size_t)2 * B_ * H_ * 2);
  float* Gi    = (float*)alloc((size_t)NROW * 3 * H_ * 4);
  float* lseA  = (float*)alloc((size_t)NROW * 4);

  hipMemsetAsync(flags, 0, 4096, stream);
  cast_bf16_kernel<<<1024, 256, 0, stream>>>(Wih, Wih16, 3 * H_ * E_ / 4);
  cast_bf16_kernel<<<1024, 256, 0, stream>>>(Whh, Whh16, 3 * H_ * H_ / 4);
  cast_bf16_kernel<<<2048, 256, 0, stream>>>(Wout, Wout16, V_ * H_ / 4);
  cast_bf16_kernel<<<32, 256, 0, stream>>>(enc_h, hb16, B_ * H_ / 4);  // h buffer 0
  embed_kernel<<<NROW / 2, 256, 0, stream>>>(tgt, emb, X16);

  // Gi = X @ W_ih^T + b_ih   (M=4096, N=3072, K=512)
  gemm_bt_kernel<<<(3 * H_ / 128) * 32, 256, 0, stream>>>(X16, Wih16, bih, Gi, E_, 3 * H_);

  recur_kernel<<<NBLK_REC, 256, 0, stream>>>(Whh16, Gi, bhh, enc_h, hb16, Hall,
                                             out + BTV, flags);

  // logits = Hall @ W_out^T + b_out -> d_out  (M=4096, N=32000, K=1024)
  gemm_bt_kernel<<<(V_ / 128) * 32, 256, 0, stream>>>(Hall, Wout16, bout, out, H_, V_);

  lse_pass1_kernel<<<NROW, 256, 0, stream>>>(out, lseA);
  lse_pass2_kernel<<<NROW, 1024, 0, stream>>>(out, lseA);
}

// Round 3
// 1501.398 us; speedup vs baseline: 2.7025x; 1.0578x over previous
//
#include <hip/hip_runtime.h>

using u16 = unsigned short;
using u32 = unsigned int;
using u64 = unsigned long long;
typedef __attribute__((ext_vector_type(8))) short bf16x8;
typedef __attribute__((ext_vector_type(4))) float f32x4;

#define B_ 32
#define T_ 128
#define E_ 512
#define H_ 1024
#define V_ 32000
#define NROW 4096                 // B*T rows, r = b*128 + t  (b-major)
#define BTV ((size_t)B_ * T_ * V_)
#define NBLK_REC 32               // recurrence blocks; each owns 32 h-columns
#define NT_STRIDE 256             // partial-LSE row stride (250 tiles used)

__device__ __forceinline__ u16 f2bf(float f) {
  u32 x = __float_as_uint(f);
  x += 0x7FFFu + ((x >> 16) & 1u);
  return (u16)(x >> 16);
}

__device__ __forceinline__ void gload_lds16(const void* g, void* l) {
  __builtin_amdgcn_global_load_lds(
      (const __attribute__((address_space(1))) u32*)g,
      (__attribute__((address_space(3))) u32*)l, 16, 0, 0);
}

// ---------------- prep: f32 -> bf16 cast (vectorized) ----------------
__global__ void cast_bf16_kernel(const float* __restrict__ src, u16* __restrict__ dst, int n4) {
  int i = blockIdx.x * blockDim.x + threadIdx.x;
  int stride = gridDim.x * blockDim.x;
  for (; i < n4; i += stride) {
    float4 v = reinterpret_cast<const float4*>(src)[i];
    u32 p0 = (u32)f2bf(v.x) | ((u32)f2bf(v.y) << 16);
    u32 p1 = (u32)f2bf(v.z) | ((u32)f2bf(v.w) << 16);
    reinterpret_cast<uint2*>(dst)[i] = make_uint2(p0, p1);
  }
}

// ---------------- prep: X = bf16(relu(emb[tok])), rows r=b*128+t ----------------
__global__ void embed_kernel(const int* __restrict__ tgt, const float* __restrict__ emb,
                             u16* __restrict__ X) {
  int r = blockIdx.x * 2 + (threadIdx.x >> 7);  // 0..4095
  int c = threadIdx.x & 127;                    // float4 index in row (E=512 -> 128)
  int t = r & 127;
  int tok = (t == 0) ? 1 : tgt[r - 1];          // BOS=1 ; tgt[b*128 + (t-1)]
  float4 v = reinterpret_cast<const float4*>(emb + (size_t)tok * E_)[c];
  u32 p0 = (u32)f2bf(fmaxf(v.x, 0.f)) | ((u32)f2bf(fmaxf(v.y, 0.f)) << 16);
  u32 p1 = (u32)f2bf(fmaxf(v.z, 0.f)) | ((u32)f2bf(fmaxf(v.w, 0.f)) << 16);
  reinterpret_cast<uint2*>(X + (size_t)r * E_)[c] = make_uint2(p0, p1);
}

// ---------------- bf16 MFMA GEMM, C[M=4096][N] = A[M][K] @ B[N][K]^T + bias ----------
// 128x128 tile, BK=32, 4 waves, global_load_lds staging (m97 structure).
// If pM != null: also emit per-(row, n-tile) LSE partials (max, sumexp).
__global__ __launch_bounds__(256)
void gemm_bt_kernel(const u16* __restrict__ A, const u16* __restrict__ B,
                    const float* __restrict__ bias, float* __restrict__ C,
                    int K, int N, float* __restrict__ pM, float* __restrict__ pS) {
  __shared__ __align__(16) u16 As[128 * 32];
  __shared__ __align__(16) u16 Bs[128 * 32];
  __shared__ float pmh[2][128], psh[2][128];
  int bid = blockIdx.x;
  int mtile = bid & 31, ntile = bid >> 5;       // grid = ntiles*32
  int m0 = mtile << 7, n0 = ntile << 7;
  int tid = threadIdx.x, wv = tid >> 6, ln = tid & 63;
  int lr = ln & 15, lg = ln >> 4;
  int wrow = (wv >> 1) << 6, wcol = (wv & 1) << 6;

  f32x4 acc[4][4];
#pragma unroll
  for (int m = 0; m < 4; ++m)
#pragma unroll
    for (int n = 0; n < 4; ++n) acc[m][n] = (f32x4){0.f, 0.f, 0.f, 0.f};

  int c0 = tid, c1 = tid + 256;
  const u16* gA0 = A + (size_t)(m0 + (c0 >> 2)) * K + ((c0 & 3) << 3);
  const u16* gA1 = A + (size_t)(m0 + (c1 >> 2)) * K + ((c1 & 3) << 3);
  const u16* gB0 = B + (size_t)(n0 + (c0 >> 2)) * K + ((c0 & 3) << 3);
  const u16* gB1 = B + (size_t)(n0 + (c1 >> 2)) * K + ((c1 & 3) << 3);
  u16* lA0 = As + (wv << 9);
  u16* lA1 = As + 2048 + (wv << 9);
  u16* lB0 = Bs + (wv << 9);
  u16* lB1 = Bs + 2048 + (wv << 9);

  for (int k0 = 0; k0 < K; k0 += 32) {
    gload_lds16(gA0 + k0, lA0);
    gload_lds16(gA1 + k0, lA1);
    gload_lds16(gB0 + k0, lB0);
    gload_lds16(gB1 + k0, lB1);
    __syncthreads();
    bf16x8 a[4], b[4];
#pragma unroll
    for (int m = 0; m < 4; ++m)
      a[m] = *reinterpret_cast<const bf16x8*>(&As[(wrow + (m << 4) + lr) * 32 + (lg << 3)]);
#pragma unroll
    for (int n = 0; n < 4; ++n)
      b[n] = *reinterpret_cast<const bf16x8*>(&Bs[(wcol + (n << 4) + lr) * 32 + (lg << 3)]);
#pragma unroll
    for (int m = 0; m < 4; ++m)
#pragma unroll
      for (int n = 0; n < 4; ++n)
        acc[m][n] = __builtin_amdgcn_mfma_f32_16x16x32_bf16(a[m], b[n], acc[m][n], 0, 0, 0);
    __syncthreads();
  }

  float bv[4];
#pragma unroll
  for (int n = 0; n < 4; ++n) bv[n] = bias[n0 + wcol + (n << 4) + lr];

#pragma unroll
  for (int m = 0; m < 4; ++m) {
#pragma unroll
    for (int i = 0; i < 4; ++i) {
      int row = wrow + (m << 4) + (lg << 2) + i;  // row within block tile
      float v[4];
#pragma unroll
      for (int n = 0; n < 4; ++n) {
        v[n] = acc[m][n][i] + bv[n];
        C[(size_t)(m0 + row) * N + n0 + wcol + (n << 4) + lr] = v[n];
      }
      if (pM) {
        float vm = fmaxf(fmaxf(v[0], v[1]), fmaxf(v[2], v[3]));
        vm = fmaxf(vm, __shfl_xor(vm, 1));
        vm = fmaxf(vm, __shfl_xor(vm, 2));
        vm = fmaxf(vm, __shfl_xor(vm, 4));
        vm = fmaxf(vm, __shfl_xor(vm, 8));
        float se = __expf(v[0] - vm) + __expf(v[1] - vm) +
                   __expf(v[2] - vm) + __expf(v[3] - vm);
        se += __shfl_xor(se, 1);
        se += __shfl_xor(se, 2);
        se += __shfl_xor(se, 4);
        se += __shfl_xor(se, 8);
        if (lr == 0) { pmh[wv & 1][row] = vm; psh[wv & 1][row] = se; }
      }
    }
  }
  if (pM) {
    __syncthreads();
    if (tid < 128) {
      float m0v = pmh[0][tid], m1v = pmh[1][tid];
      float M = fmaxf(m0v, m1v);
      float S = psh[0][tid] * __expf(m0v - M) + psh[1][tid] * __expf(m1v - M);
      pM[(size_t)(m0 + tid) * NT_STRIDE + ntile] = M;
      pS[(size_t)(m0 + tid) * NT_STRIDE + ntile] = S;
    }
  }
}

// ---------------- persistent GRU recurrence, 32 blocks, relaxed sc1 exchange ------
__device__ __forceinline__ float sigm(float x) { return 1.f / (1.f + __expf(-x)); }

__global__ __launch_bounds__(256, 1)
void recur_kernel(const u16* __restrict__ Whh16, const float* __restrict__ Gi,
                  const float* __restrict__ bhh, const float* __restrict__ enc_h,
                  u16* __restrict__ hb16, u16* __restrict__ Hall,
                  float* __restrict__ outTail, u32* __restrict__ flags) {
  int bid = blockIdx.x;               // 0..31 ; owns h columns [bid*32, bid*32+32)
  int tid = threadIdx.x, wv = tid >> 6, ln = tid & 63;
  int lr = ln & 15, lg = ln >> 4;
  int j0 = bid << 5;
  int kb = wv << 8;                   // K-slice per wave: 256

  __shared__ float red[4][2][6][256]; // [wave][Mtile][Ntile(g*2+nh)][row16*16+col16]

  // preload W_hh fragments: 6 N-tiles (3 gates x 2) x 8 kk = 192 regs/lane
  bf16x8 wf[6][8];
#pragma unroll
  for (int g = 0; g < 3; ++g)
#pragma unroll
    for (int nh = 0; nh < 2; ++nh) {
      const u16* wrow = Whh16 + (size_t)(g * H_ + j0 + nh * 16 + lr) * H_ + kb + (lg << 3);
#pragma unroll
      for (int kk = 0; kk < 8; ++kk)
        wf[g * 2 + nh][kk] = *reinterpret_cast<const bf16x8*>(wrow + kk * 32);
    }

  // gate-math ownership: thread -> (batch bb, 4 cols j0+j4..j0+j4+3)
  int bb = tid >> 3;
  int j4 = (tid & 7) << 2;
  float4 bhr = *reinterpret_cast<const float4*>(bhh + 0 * H_ + j0 + j4);
  float4 bhz = *reinterpret_cast<const float4*>(bhh + 1 * H_ + j0 + j4);
  float4 bhn = *reinterpret_cast<const float4*>(bhh + 2 * H_ + j0 + j4);
  float4 hp = *reinterpret_cast<const float4*>(enc_h + bb * H_ + j0 + j4);

  for (int t = 0; t < T_; ++t) {
    int cur = t & 1, nxt = cur ^ 1;

    // Gi prefetch (independent of h) -- issued before the poll
    const float* gib = Gi + (size_t)(bb * T_ + t) * (3 * H_) + j0 + j4;
    float4 gir = *reinterpret_cast<const float4*>(gib + 0 * H_);
    float4 giz = *reinterpret_cast<const float4*>(gib + 1 * H_);
    float4 gin = *reinterpret_cast<const float4*>(gib + 2 * H_);

    if (t > 0) {
      // per-wave dependency poll: this wave's K-slice is written by blocks
      // wv*8 .. wv*8+7 ; lanes 0..7 poll, exec-reconvergence holds the wave.
      if (ln < 8) {
        while (__hip_atomic_load(&flags[(wv * 8 + ln) * 16], __ATOMIC_RELAXED,
                                 __HIP_MEMORY_SCOPE_AGENT) < (u32)t)
          __builtin_amdgcn_s_sleep(1);
      }
    }

    // per-wave K-slice GEMV: relaxed-agent (sc1, L2-bypass) fragment loads
    const u16* hbase = hb16 + (size_t)cur * (B_ * H_) + kb + (lg << 3);
    f32x4 acc[2][6];
#pragma unroll
    for (int mt = 0; mt < 2; ++mt)
#pragma unroll
      for (int tn = 0; tn < 6; ++tn) acc[mt][tn] = (f32x4){0.f, 0.f, 0.f, 0.f};
#pragma unroll
    for (int kk = 0; kk < 8; ++kk) {
      const u64* p0 = reinterpret_cast<const u64*>(hbase + (size_t)lr * H_ + kk * 32);
      const u64* p1 = reinterpret_cast<const u64*>(hbase + (size_t)(16 + lr) * H_ + kk * 32);
      union { u64 q[2]; bf16x8 v; } A0, A1;
      A0.q[0] = __hip_atomic_load(p0, __ATOMIC_RELAXED, __HIP_MEMORY_SCOPE_AGENT);
      A0.q[1] = __hip_atomic_load(p0 + 1, __ATOMIC_RELAXED, __HIP_MEMORY_SCOPE_AGENT);
      A1.q[0] = __hip_atomic_load(p1, __ATOMIC_RELAXED, __HIP_MEMORY_SCOPE_AGENT);
      A1.q[1] = __hip_atomic_load(p1 + 1, __ATOMIC_RELAXED, __HIP_MEMORY_SCOPE_AGENT);
#pragma unroll
      for (int tn = 0; tn < 6; ++tn) {
        acc[0][tn] = __builtin_amdgcn_mfma_f32_16x16x32_bf16(A0.v, wf[tn][kk], acc[0][tn], 0, 0, 0);
        acc[1][tn] = __builtin_amdgcn_mfma_f32_16x16x32_bf16(A1.v, wf[tn][kk], acc[1][tn], 0, 0, 0);
      }
    }

    // cross-wave K reduction in LDS
#pragma unroll
    for (int mt = 0; mt < 2; ++mt)
#pragma unroll
      for (int tn = 0; tn < 6; ++tn)
#pragma unroll
        for (int i = 0; i < 4; ++i)
          red[wv][mt][tn][((lg << 2) + i) * 16 + lr] = acc[mt][tn][i];
    __syncthreads();

    int mt = bb >> 4;
    int nh = j4 >> 4;
    int rbase = (bb & 15) * 16 + (j4 & 15);
    float4 s[3];
#pragma unroll
    for (int g = 0; g < 3; ++g) {
      float4 a4 = make_float4(0.f, 0.f, 0.f, 0.f);
#pragma unroll
      for (int w = 0; w < 4; ++w) {
        float4 v = *reinterpret_cast<const float4*>(&red[w][mt][g * 2 + nh][rbase]);
        a4.x += v.x; a4.y += v.y; a4.z += v.z; a4.w += v.w;
      }
      s[g] = a4;
    }

    // gate math (4 elements)
    float hn[4];
    {
      float r0 = sigm(gir.x + s[0].x + bhr.x);
      float r1 = sigm(gir.y + s[0].y + bhr.y);
      float r2 = sigm(gir.z + s[0].z + bhr.z);
      float r3 = sigm(gir.w + s[0].w + bhr.w);
      float z0 = sigm(giz.x + s[1].x + bhz.x);
      float z1 = sigm(giz.y + s[1].y + bhz.y);
      float z2 = sigm(giz.z + s[1].z + bhz.z);
      float z3 = sigm(giz.w + s[1].w + bhz.w);
      float a0 = gin.x + r0 * (s[2].x + bhn.x);
      float a1 = gin.y + r1 * (s[2].y + bhn.y);
      float a2 = gin.z + r2 * (s[2].z + bhn.z);
      float a3 = gin.w + r3 * (s[2].w + bhn.w);
      float n0 = 2.f / (1.f + __expf(-2.f * a0)) - 1.f;
      float n1 = 2.f / (1.f + __expf(-2.f * a1)) - 1.f;
      float n2 = 2.f / (1.f + __expf(-2.f * a2)) - 1.f;
      float n3 = 2.f / (1.f + __expf(-2.f * a3)) - 1.f;
      hn[0] = (1.f - z0) * n0 + z0 * hp.x;
      hn[1] = (1.f - z1) * n1 + z1 * hp.y;
      hn[2] = (1.f - z2) * n2 + z2 * hp.z;
      hn[3] = (1.f - z3) * n3 + z3 * hp.w;
      hp = make_float4(hn[0], hn[1], hn[2], hn[3]);
    }

    u32 p0 = (u32)f2bf(hn[0]) | ((u32)f2bf(hn[1]) << 16);
    u32 p1 = (u32)f2bf(hn[2]) | ((u32)f2bf(hn[3]) << 16);

    // Hall (consumed by later kernel; plain cached store)
    reinterpret_cast<uint2*>(Hall + (size_t)(bb * T_ + t) * H_ + j0 + j4)[0] = make_uint2(p0, p1);

    if (t < T_ - 1) {
      // h exchange: relaxed agent-scope u64 store (sc1, write-through to L3)
      u64 pv = (u64)p0 | ((u64)p1 << 32);
      u64* hw = reinterpret_cast<u64*>(hb16 + (size_t)nxt * (B_ * H_) + bb * H_ + j0 + j4);
      __hip_atomic_store(hw, pv, __ATOMIC_RELAXED, __HIP_MEMORY_SCOPE_AGENT);
      // barrier: (a) red reads done before next step's writes,
      //          (b) vmcnt(0) drain -> all sc1 stores committed at L3
      __syncthreads();
      if (tid == 0)
        __hip_atomic_store(&flags[bid * 16], (u32)(t + 1), __ATOMIC_RELAXED,
                           __HIP_MEMORY_SCOPE_AGENT);
    } else {
      reinterpret_cast<float4*>(outTail + (size_t)bb * H_ + j0 + j4)[0] = hp;
    }
  }
}

// ---------------- LSE combine: merge 250 per-tile partials per row ----------------
__global__ __launch_bounds__(256)
void lse_combine_kernel(const float* __restrict__ pM, const float* __restrict__ pS,
                        float* __restrict__ lse) {
  int r = blockIdx.x;
  int t = threadIdx.x;
  float M = -3.0e38f, S = 0.f;
  if (t < 250) { M = pM[(size_t)r * NT_STRIDE + t]; S = pS[(size_t)r * NT_STRIDE + t]; }
#pragma unroll
  for (int o = 32; o; o >>= 1) {
    float Mo = __shfl_xor(M, o);
    float So = __shfl_xor(S, o);
    float Mn = fmaxf(M, Mo);
    S = S * __expf(M - Mn) + So * __expf(Mo - Mn);
    M = Mn;
  }
  __shared__ float tM[4], tS[4];
  if ((t & 63) == 0) { tM[t >> 6] = M; tS[t >> 6] = S; }
  __syncthreads();
  if (t == 0) {
    float Mf = tM[0], Sf = tS[0];
    for (int w = 1; w < 4; ++w) {
      float Mn = fmaxf(Mf, tM[w]);
      Sf = Sf * __expf(Mf - Mn) + tS[w] * __expf(tM[w] - Mn);
      Mf = Mn;
    }
    lse[r] = Mf + __logf(Sf);
  }
}

// ---------------- log-softmax: pass2 subtract ----------------
__global__ __launch_bounds__(1024)
void lse_pass2_kernel(float* __restrict__ out, const float* __restrict__ lse) {
  int r = blockIdx.x;
  float l = lse[r];
  float4* p = reinterpret_cast<float4*>(out + (size_t)r * V_);
  for (int i = threadIdx.x; i < V_ / 4; i += 1024) {
    float4 v = p[i];
    v.x -= l; v.y -= l; v.z -= l; v.w -= l;
    p[i] = v;
  }
}

// ---------------- host ----------------
extern "C" void kernel_launch(void* const* d_in, const int* in_sizes, int n_in,
                              void* d_out, int out_size, void* d_ws, size_t ws_size,
                              hipStream_t stream) {
  const float* enc_h = (const float*)d_in[1];
  const int*   tgt   = (const int*)d_in[2];
  const float* emb   = (const float*)d_in[3];
  const float* Wih   = (const float*)d_in[4];
  const float* Whh   = (const float*)d_in[5];
  const float* bih   = (const float*)d_in[6];
  const float* bhh   = (const float*)d_in[7];
  const float* Wout  = (const float*)d_in[8];
  const float* bout  = (const float*)d_in[9];
  float* out = (float*)d_out;

  char* ws = (char*)d_ws;
  size_t off = 0;
  auto alloc = [&](size_t bytes) -> void* {
    void* p = ws + off;
    off = (off + bytes + 255) & ~(size_t)255;
    return p;
  };
  u32*  flags  = (u32*)alloc(4096);
  u16*  Wih16  = (u16*)alloc((size_t)3 * H_ * E_ * 2);
  u16*  Whh16  = (u16*)alloc((size_t)3 * H_ * H_ * 2);
  u16*  Wout16 = (u16*)alloc((size_t)V_ * H_ * 2);
  u16*  X16    = (u16*)alloc((size_t)NROW * E_ * 2);
  u16*  Hall   = (u16*)alloc((size_t)NROW * H_ * 2);
  u16*  hb16   = (u16*)alloc((size_t)2 * B_ * H_ * 2);
  float* Gi    = (float*)alloc((size_t)NROW * 3 * H_ * 4);
  float* lseA  = (float*)alloc((size_t)NROW * 4);
  float* pM    = (float*)alloc((size_t)NROW * NT_STRIDE * 4);
  float* pS    = (float*)alloc((size_t)NROW * NT_STRIDE * 4);

  hipMemsetAsync(flags, 0, 4096, stream);
  cast_bf16_kernel<<<1024, 256, 0, stream>>>(Wih, Wih16, 3 * H_ * E_ / 4);
  cast_bf16_kernel<<<1024, 256, 0, stream>>>(Whh, Whh16, 3 * H_ * H_ / 4);
  cast_bf16_kernel<<<2048, 256, 0, stream>>>(Wout, Wout16, V_ * H_ / 4);
  cast_bf16_kernel<<<32, 256, 0, stream>>>(enc_h, hb16, B_ * H_ / 4);  // h buffer 0
  embed_kernel<<<NROW / 2, 256, 0, stream>>>(tgt, emb, X16);

  // Gi = X @ W_ih^T + b_ih   (M=4096, N=3072, K=512)
  gemm_bt_kernel<<<(3 * H_ / 128) * 32, 256, 0, stream>>>(X16, Wih16, bih, Gi, E_, 3 * H_,
                                                          nullptr, nullptr);

  recur_kernel<<<NBLK_REC, 256, 0, stream>>>(Whh16, Gi, bhh, enc_h, hb16, Hall,
                                             out + BTV, flags);

  // logits = Hall @ W_out^T + b_out -> d_out, fused LSE partials
  gemm_bt_kernel<<<(V_ / 128) * 32, 256, 0, stream>>>(Hall, Wout16, bout, out, H_, V_,
                                                      pM, pS);

  lse_combine_kernel<<<NROW, 256, 0, stream>>>(pM, pS, lseA);
  lse_pass2_kernel<<<NROW, 1024, 0, stream>>>(out, lseA);
}